// Round 2
// baseline (857.270 us; speedup 1.0000x reference)
//
#include <hip/hip_runtime.h>
#include <math.h>

// Problem constants: B=8, spatial 64x64 (HW=4096), C_mid=256, C=128, N=9 taps.
// All inputs/outputs are float32 (per reference setup_inputs / return dtype).
typedef const float* fp;

// ---------------- K0: transpose dcn_w (128,128,9) -> Wt[k=1152][o=128]
__global__ __launch_bounds__(256) void k_wt(fp dcn_w, float* Wt){
    int i = blockIdx.x*256 + threadIdx.x;       // 147456
    int k = i >> 7, o = i & 127;
    Wt[i] = dcn_w[o*1152 + k];
}

// ---------------- K1: bilinear up2x(align_corners) of x1 + concat with x2 -> A (8,256,64,64)
__global__ __launch_bounds__(256) void k_concat_up(fp x1, fp x2, float* A){
    int idx = blockIdx.x*256 + threadIdx.x;     // 8,388,608
    int x = idx & 63, y = (idx>>6)&63, c = (idx>>12)&255, b = idx>>20;
    float val;
    if (c < 128){
        val = x2[((b*128+c)<<12) + (y<<6) + x];
    } else {
        int cc = c - 128;
        const float s = 31.0f/63.0f;
        float fy = y*s, fx = x*s;
        int iy = (int)fy; if (iy > 30) iy = 30;
        int ix = (int)fx; if (ix > 30) ix = 30;
        float ty = fy - (float)iy, tx = fx - (float)ix;
        fp src = x1 + ((b*128+cc)<<10);
        float v00 = src[iy*32+ix],     v01 = src[iy*32+ix+1];
        float v10 = src[(iy+1)*32+ix], v11 = src[(iy+1)*32+ix+1];
        val = (v00*(1.f-ty)+v10*ty)*(1.f-tx) + (v01*(1.f-ty)+v11*ty)*tx;
    }
    A[idx] = val;
}

// ---------------- K2: depthwise 3x3 SAME over 256 ch + bias -> Bo
__global__ __launch_bounds__(256) void k_dw256(const float* A, fp w, fp bias, float* Bo){
    int idx = blockIdx.x*256 + threadIdx.x;     // 8,388,608
    int x = idx&63, y=(idx>>6)&63, c=(idx>>12)&255, b=idx>>20;
    const float* src = A + ((b*256+c)<<12);
    float acc = bias[c];
    #pragma unroll
    for(int ky=0; ky<3; ky++){
        int yy = y+ky-1; if(yy<0||yy>63) continue;
        #pragma unroll
        for(int kx=0; kx<3; kx++){
            int xx = x+kx-1; if(xx<0||xx>63) continue;
            acc += src[(yy<<6)+xx]*w[c*9+ky*3+kx];
        }
    }
    Bo[idx] = acc;
}

// ---------------- K3: pointwise 256->128 + bias -> C.  Block: 32 px, 128 o; thread 4o x 4px.
__global__ __launch_bounds__(256) void k_pw(const float* Bi, fp w, fp bias, float* Co){
    __shared__ float sIn[256*32];
    int bid = blockIdx.x;                       // 1024
    int b = bid >> 7;
    int pix0 = (bid & 127) << 5;
    int tid = threadIdx.x;
    for(int j = tid; j < 256*32; j += 256){
        int c = j >> 5, p = j & 31;
        sIn[j] = Bi[((b*256 + c)<<12) + pix0 + p];
    }
    __syncthreads();
    int og = tid >> 3, pg = tid & 7;
    int o0 = og*4, p0 = pg*4;
    float acc[4][4];
    #pragma unroll
    for(int i=0;i<4;i++){ float bv=bias[o0+i];
        #pragma unroll
        for(int j=0;j<4;j++) acc[i][j]=bv; }
    for(int c=0;c<256;c++){
        float4 xv = *(const float4*)&sIn[(c<<5)+p0];
        float w0=w[(o0+0)*256+c], w1=w[(o0+1)*256+c];
        float w2=w[(o0+2)*256+c], w3=w[(o0+3)*256+c];
        acc[0][0]+=w0*xv.x; acc[0][1]+=w0*xv.y; acc[0][2]+=w0*xv.z; acc[0][3]+=w0*xv.w;
        acc[1][0]+=w1*xv.x; acc[1][1]+=w1*xv.y; acc[1][2]+=w1*xv.z; acc[1][3]+=w1*xv.w;
        acc[2][0]+=w2*xv.x; acc[2][1]+=w2*xv.y; acc[2][2]+=w2*xv.z; acc[2][3]+=w2*xv.w;
        acc[3][0]+=w3*xv.x; acc[3][1]+=w3*xv.y; acc[3][2]+=w3*xv.z; acc[3][3]+=w3*xv.w;
    }
    #pragma unroll
    for(int i=0;i<4;i++){
        *(float4*)&Co[((b*128+o0+i)<<12)+pix0+p0] =
            make_float4(acc[i][0],acc[i][1],acc[i][2],acc[i][3]);
    }
}

// ---------------- K4: offset conv (18ch) + mask conv (9ch, sigmoid) 3x3 SAME -> OM (8,27,4096)
__global__ __launch_bounds__(256) void k_offmask(const float* Cin, fp pw, fp pb, fp mw, fp mb, float* OM){
    int idx = blockIdx.x*256 + threadIdx.x;     // 221,184  (thread = one q, 4 px)
    int xg = idx & 15; int t = idx >> 4; int y = t & 63; t >>= 6; int q = t % 27; int b = t / 27;
    int x0 = xg << 2;
    const float* W; float bias;
    if(q < 18){ W = pw + q*1152; bias = pb[q]; }
    else      { W = mw + (q-18)*1152; bias = mb[q-18]; }
    float acc0=bias, acc1=bias, acc2=bias, acc3=bias;
    const float* base = Cin + ((b*128)<<12);
    for(int c=0;c<128;c++){
        const float* plane = base + (c<<12);
        const float* wc = W + c*9;
        #pragma unroll
        for(int ky=0;ky<3;ky++){
            int yy = y+ky-1; if(yy<0||yy>63) continue;
            const float* row = plane + (yy<<6);
            float4 vm = *(const float4*)&row[x0];
            float vl = (x0>0)  ? row[x0-1] : 0.0f;
            float vr = (x0<60) ? row[x0+4] : 0.0f;
            float w0=wc[ky*3+0], w1=wc[ky*3+1], w2=wc[ky*3+2];
            acc0 += w0*vl   + w1*vm.x + w2*vm.y;
            acc1 += w0*vm.x + w1*vm.y + w2*vm.z;
            acc2 += w0*vm.y + w1*vm.z + w2*vm.w;
            acc3 += w0*vm.z + w1*vm.w + w2*vr;
        }
    }
    if(q>=18){
        acc0 = 1.f/(1.f+expf(-acc0)); acc1 = 1.f/(1.f+expf(-acc1));
        acc2 = 1.f/(1.f+expf(-acc2)); acc3 = 1.f/(1.f+expf(-acc3));
    }
    float* dst = OM + ((b*27+q)<<12) + (y<<6) + x0;
    dst[0]=acc0; dst[1]=acc1; dst[2]=acc2; dst[3]=acc3;
}

// ---------------- K5: deformable sampling + (128 x 1152) combine -> D (8,128,4096)
// Block: 32 px, all 128 outputs; thread 4o x 4px; x_off staged per 16-channel chunk in LDS.
__global__ __launch_bounds__(256) void k_deform(const float* hC, const float* OM, const float* Wt, float* D){
    __shared__ int   sIdx[4*288];
    __shared__ float sG[4*288];
    __shared__ float sX[144*32];
    int bid = blockIdx.x;                       // 1024
    int b = bid >> 7; int pix0 = (bid & 127) << 5;
    int tid = threadIdx.x;
    const float* omb = OM + ((b*27)<<12);
    for(int i = tid; i < 288; i += 256){
        int p = i / 9, n = i - p*9;
        int pix = pix0 + p; int y = pix >> 6; int x = pix & 63;
        float offx = omb[(n<<12) + pix];
        float offy = omb[((n+9)<<12) + pix];
        float m    = omb[((n+18)<<12) + pix];
        float pxf = (float)(y+1) + (float)(n/3 - 1) + offx;   // row coord in padded img
        float pyf = (float)(x+1) + (float)(n%3 - 1) + offy;   // col coord
        float fx = floorf(pxf), fy = floorf(pyf);
        float qx0 = fminf(fmaxf(fx,0.f),65.f),     qx1 = fminf(fmaxf(fx+1.f,0.f),65.f);
        float qy0 = fminf(fmaxf(fy,0.f),65.f),     qy1 = fminf(fmaxf(fy+1.f,0.f),65.f);
        float pxc = fminf(fmaxf(pxf,0.f),65.f),    pyc = fminf(fmaxf(pyf,0.f),65.f);
        float glt = (1.f+(qx0-pxc))*(1.f+(qy0-pyc)) * m;
        float grb = (1.f-(qx1-pxc))*(1.f-(qy1-pyc)) * m;
        float glb = (1.f+(qx0-pxc))*(1.f-(qy1-pyc)) * m;
        float grt = (1.f-(qx1-pxc))*(1.f+(qy0-pyc)) * m;
        int ax0=(int)qx0, ax1=(int)qx1, ay0=(int)qy0, ay1=(int)qy1;
        sIdx[i]     = (ax0>=1&&ax0<=64&&ay0>=1&&ay0<=64) ? (((ax0-1)<<6)+(ay0-1)) : -1;
        sIdx[288+i] = (ax1>=1&&ax1<=64&&ay1>=1&&ay1<=64) ? (((ax1-1)<<6)+(ay1-1)) : -1;
        sIdx[576+i] = (ax0>=1&&ax0<=64&&ay1>=1&&ay1<=64) ? (((ax0-1)<<6)+(ay1-1)) : -1;
        sIdx[864+i] = (ax1>=1&&ax1<=64&&ay0>=1&&ay0<=64) ? (((ax1-1)<<6)+(ay0-1)) : -1;
        sG[i]=glt; sG[288+i]=grb; sG[576+i]=glb; sG[864+i]=grt;
    }
    __syncthreads();
    int og = tid >> 3, pg = tid & 7; int o0 = og*4, p0 = pg*4;
    float acc[4][4] = {{0.f}};
    const float* hb = hC + ((b*128)<<12);
    for(int cc=0; cc<128; cc+=16){
        for(int j = tid; j < 144*32; j += 256){
            int kl = j >> 5, p = j & 31;
            int cq = kl/9; int c = cc + cq, n = kl - cq*9;
            int it = p*9 + n;
            const float* plane = hb + (c<<12);
            int i0=sIdx[it], i1=sIdx[288+it], i2=sIdx[576+it], i3=sIdx[864+it];
            float v = 0.f;
            if(i0>=0) v += sG[it]    *plane[i0];
            if(i1>=0) v += sG[288+it]*plane[i1];
            if(i2>=0) v += sG[576+it]*plane[i2];
            if(i3>=0) v += sG[864+it]*plane[i3];
            sX[j] = v;
        }
        __syncthreads();
        const float* wt = Wt + (cc*9)*128;
        for(int kl=0; kl<144; kl++){
            float4 w4 = *(const float4*)&wt[kl*128 + o0];
            float4 x4 = *(const float4*)&sX[(kl<<5) + p0];
            acc[0][0]+=w4.x*x4.x; acc[0][1]+=w4.x*x4.y; acc[0][2]+=w4.x*x4.z; acc[0][3]+=w4.x*x4.w;
            acc[1][0]+=w4.y*x4.x; acc[1][1]+=w4.y*x4.y; acc[1][2]+=w4.y*x4.z; acc[1][3]+=w4.y*x4.w;
            acc[2][0]+=w4.z*x4.x; acc[2][1]+=w4.z*x4.y; acc[2][2]+=w4.z*x4.z; acc[2][3]+=w4.z*x4.w;
            acc[3][0]+=w4.w*x4.x; acc[3][1]+=w4.w*x4.y; acc[3][2]+=w4.w*x4.z; acc[3][3]+=w4.w*x4.w;
        }
        __syncthreads();
    }
    #pragma unroll
    for(int i=0;i<4;i++){
        *(float4*)&D[((b*128+o0+i)<<12)+pix0+p0] =
            make_float4(acc[i][0],acc[i][1],acc[i][2],acc[i][3]);
    }
}

// ---------------- stats: per-channel mean & rstd (training BN, biased var)
__global__ __launch_bounds__(256) void k_stats(const float* src, float* stats, int statOfs){
    __shared__ double sd[256], sq[256];
    int c = blockIdx.x, tid = threadIdx.x;
    double s=0.0, s2=0.0;
    for(int b=0;b<8;b++){
        const float* p = src + ((b*128+c)<<12);
        for(int i=tid;i<4096;i+=256){ double v = (double)p[i]; s+=v; s2+=v*v; }
    }
    sd[tid]=s; sq[tid]=s2; __syncthreads();
    for(int off=128; off>0; off>>=1){
        if(tid<off){ sd[tid]+=sd[tid+off]; sq[tid]+=sq[tid+off]; }
        __syncthreads();
    }
    if(tid==0){
        double mean = sd[0]/32768.0;
        double var  = sq[0]/32768.0 - mean*mean;
        stats[statOfs+c]     = (float)mean;
        stats[statOfs+128+c] = rsqrtf((float)var + 1e-5f);
    }
}

// ---------------- BN1 + exact GELU
__global__ __launch_bounds__(256) void k_bn_gelu(const float* D, const float* stats, fp g, fp bb, float* G){
    int idx = blockIdx.x*256+threadIdx.x;       // 4,194,304
    int c = (idx>>12)&127;
    float v = (D[idx]-stats[c])*stats[128+c]*g[c] + bb[c];
    G[idx] = 0.5f*v*(1.0f+erff(v*0.70710678118654752f));
}

// ---------------- depthwise 3x3 over 128 ch + bias
__global__ __launch_bounds__(256) void k_dw128(const float* G, fp w, fp bias, float* Hs){
    int idx = blockIdx.x*256 + threadIdx.x;     // 4,194,304
    int x = idx&63, y=(idx>>6)&63, c=(idx>>12)&127, b=idx>>19;
    const float* src = G + ((b*128+c)<<12);
    float acc = bias[c];
    #pragma unroll
    for(int ky=0; ky<3; ky++){
        int yy = y+ky-1; if(yy<0||yy>63) continue;
        #pragma unroll
        for(int kx=0; kx<3; kx++){
            int xx = x+kx-1; if(xx<0||xx>63) continue;
            acc += src[(yy<<6)+xx]*w[c*9+ky*3+kx];
        }
    }
    Hs[idx] = acc;
}

// ---------------- BN2 + ReLU -> f32 out
__global__ __launch_bounds__(256) void k_bn_relu_out(const float* Hs, const float* stats, fp g, fp bb, float* out){
    int idx = blockIdx.x*256+threadIdx.x;       // 4,194,304
    int c = (idx>>12)&127;
    float v = (Hs[idx]-stats[256+c])*stats[384+c]*g[c] + bb[c];
    out[idx] = fmaxf(v,0.f);
}

extern "C" void kernel_launch(void* const* d_in, const int* in_sizes, int n_in,
                              void* d_out, int out_size, void* d_ws, size_t ws_size,
                              hipStream_t stream){
    fp x1   = (fp)d_in[0];
    fp x2   = (fp)d_in[1];
    fp dw_w = (fp)d_in[2];  fp dw_b = (fp)d_in[3];
    fp pw_w = (fp)d_in[4];  fp pw_b = (fp)d_in[5];
    fp p_w  = (fp)d_in[6];  fp p_b  = (fp)d_in[7];
    fp m_w  = (fp)d_in[8];  fp m_b  = (fp)d_in[9];
    fp dcn_w= (fp)d_in[10];
    fp bn1g = (fp)d_in[11]; fp bn1b = (fp)d_in[12];
    fp dw2w = (fp)d_in[13]; fp dw2b = (fp)d_in[14];
    fp bn2g = (fp)d_in[15]; fp bn2b = (fp)d_in[16];

    float* ws    = (float*)d_ws;
    float* A     = ws;                  // 8,388,608 f  (xcat; later OM / G / Hs)
    float* Bo    = ws + 8388608;        // 8,388,608 f  (xdw;  later D)
    float* C     = ws + 16777216;       // 4,194,304 f  (h after pointwise)
    float* Wt    = ws + 20971520;       //   147,456 f  (transposed dcn_w)
    float* stats = ws + 21118976;       //       512 f
    float* OM = A;                      // (8,27,4096) — A is dead after k_dw256
    float* D  = Bo;                     // (8,128,4096) — Bo dead after k_pw
    float* G  = A;                      // overwrites OM after k_deform
    float* Hs = A + 4194304;
    float* out = (float*)d_out;

    k_wt        <<<576,   256, 0, stream>>>(dcn_w, Wt);
    k_concat_up <<<32768, 256, 0, stream>>>(x1, x2, A);
    k_dw256     <<<32768, 256, 0, stream>>>(A, dw_w, dw_b, Bo);
    k_pw        <<<1024,  256, 0, stream>>>(Bo, pw_w, pw_b, C);
    k_offmask   <<<864,   256, 0, stream>>>(C, p_w, p_b, m_w, m_b, OM);
    k_deform    <<<1024,  256, 0, stream>>>(C, OM, Wt, D);
    k_stats     <<<128,   256, 0, stream>>>(D, stats, 0);
    k_bn_gelu   <<<16384, 256, 0, stream>>>(D, stats, bn1g, bn1b, G);
    k_dw128     <<<16384, 256, 0, stream>>>(G, dw2w, dw2b, Hs);
    k_stats     <<<128,   256, 0, stream>>>(Hs, stats, 256);
    k_bn_relu_out<<<16384,256, 0, stream>>>(Hs, stats, bn2g, bn2b, out);
}

// Round 4
// 765.597 us; speedup vs baseline: 1.1197x; 1.1197x over previous
//
#include <hip/hip_runtime.h>
#include <math.h>

// Problem constants: B=8, spatial 64x64 (HW=4096), C_mid=256, C=128, N=9 taps.
// All inputs/outputs are float32.
typedef const float* fp;

// ---------------- K0: dcn_w (o,c,9) -> Wt2[n][c][o] f32 (tap-major for per-tap combine)
__global__ __launch_bounds__(256) void k_wt2(fp dcn_w, float* Wt2){
    int i = blockIdx.x*256 + threadIdx.x;       // 147456
    int o = i & 127, c = (i >> 7) & 127, n = i >> 14;
    Wt2[i] = dcn_w[o*1152 + c*9 + n];
}

// ---------------- K1: bilinear up2x(align_corners) of x1 + concat with x2 -> A (8,256,64,64)
__global__ __launch_bounds__(256) void k_concat_up(fp x1, fp x2, float* A){
    int idx = blockIdx.x*256 + threadIdx.x;     // 8,388,608
    int x = idx & 63, y = (idx>>6)&63, c = (idx>>12)&255, b = idx>>20;
    float val;
    if (c < 128){
        val = x2[((b*128+c)<<12) + (y<<6) + x];
    } else {
        int cc = c - 128;
        const float s = 31.0f/63.0f;
        float fy = y*s, fx = x*s;
        int iy = (int)fy; if (iy > 30) iy = 30;
        int ix = (int)fx; if (ix > 30) ix = 30;
        float ty = fy - (float)iy, tx = fx - (float)ix;
        fp src = x1 + ((b*128+cc)<<10);
        float v00 = src[iy*32+ix],     v01 = src[iy*32+ix+1];
        float v10 = src[(iy+1)*32+ix], v11 = src[(iy+1)*32+ix+1];
        val = (v00*(1.f-ty)+v10*ty)*(1.f-tx) + (v01*(1.f-ty)+v11*ty)*tx;
    }
    A[idx] = val;
}

// ---------------- K2: depthwise 3x3 SAME over 256 ch + bias -> Bo
__global__ __launch_bounds__(256) void k_dw256(const float* A, fp w, fp bias, float* Bo){
    int idx = blockIdx.x*256 + threadIdx.x;     // 8,388,608
    int x = idx&63, y=(idx>>6)&63, c=(idx>>12)&255, b=idx>>20;
    const float* src = A + ((b*256+c)<<12);
    float acc = bias[c];
    #pragma unroll
    for(int ky=0; ky<3; ky++){
        int yy = y+ky-1; if(yy<0||yy>63) continue;
        #pragma unroll
        for(int kx=0; kx<3; kx++){
            int xx = x+kx-1; if(xx<0||xx>63) continue;
            acc += src[(yy<<6)+xx]*w[c*9+ky*3+kx];
        }
    }
    Bo[idx] = acc;
}

// ---------------- K3: pointwise 256->128 + bias -> C (ch-major) AND Ccl (ch-last)
__global__ __launch_bounds__(256) void k_pw(const float* Bi, fp w, fp bias, float* Co, float* Ccl){
    __shared__ float sIn[256*32];
    int bid = blockIdx.x;                       // 1024
    int b = bid >> 7;
    int pix0 = (bid & 127) << 5;
    int tid = threadIdx.x;
    for(int j = tid; j < 256*32; j += 256){
        int c = j >> 5, p = j & 31;
        sIn[j] = Bi[((b*256 + c)<<12) + pix0 + p];
    }
    __syncthreads();
    int og = tid >> 3, pg = tid & 7;
    int o0 = og*4, p0 = pg*4;
    float acc[4][4];
    #pragma unroll
    for(int i=0;i<4;i++){ float bv=bias[o0+i];
        #pragma unroll
        for(int j=0;j<4;j++) acc[i][j]=bv; }
    for(int c=0;c<256;c++){
        float4 xv = *(const float4*)&sIn[(c<<5)+p0];
        float w0=w[(o0+0)*256+c], w1=w[(o0+1)*256+c];
        float w2=w[(o0+2)*256+c], w3=w[(o0+3)*256+c];
        acc[0][0]+=w0*xv.x; acc[0][1]+=w0*xv.y; acc[0][2]+=w0*xv.z; acc[0][3]+=w0*xv.w;
        acc[1][0]+=w1*xv.x; acc[1][1]+=w1*xv.y; acc[1][2]+=w1*xv.z; acc[1][3]+=w1*xv.w;
        acc[2][0]+=w2*xv.x; acc[2][1]+=w2*xv.y; acc[2][2]+=w2*xv.z; acc[2][3]+=w2*xv.w;
        acc[3][0]+=w3*xv.x; acc[3][1]+=w3*xv.y; acc[3][2]+=w3*xv.z; acc[3][3]+=w3*xv.w;
    }
    #pragma unroll
    for(int i=0;i<4;i++){
        *(float4*)&Co[((b*128+o0+i)<<12)+pix0+p0] =
            make_float4(acc[i][0],acc[i][1],acc[i][2],acc[i][3]);
    }
    #pragma unroll
    for(int j=0;j<4;j++){
        int px = pix0 + p0 + j;
        *(float4*)&Ccl[((size_t)(b<<12) + px)*128 + o0] =
            make_float4(acc[0][j],acc[1][j],acc[2][j],acc[3][j]);
    }
}

// ---------------- K4: offset conv (18ch) + mask conv (9ch, sigmoid) 3x3 SAME -> OM (8,27,4096)
__global__ __launch_bounds__(256) void k_offmask(const float* Cin, fp pw, fp pb, fp mw, fp mb, float* OM){
    int idx = blockIdx.x*256 + threadIdx.x;     // 221,184  (thread = one q, 4 px)
    int xg = idx & 15; int t = idx >> 4; int y = t & 63; t >>= 6; int q = t % 27; int b = t / 27;
    int x0 = xg << 2;
    const float* W; float bias;
    if(q < 18){ W = pw + q*1152; bias = pb[q]; }
    else      { W = mw + (q-18)*1152; bias = mb[q-18]; }
    float acc0=bias, acc1=bias, acc2=bias, acc3=bias;
    const float* base = Cin + ((b*128)<<12);
    for(int c=0;c<128;c++){
        const float* plane = base + (c<<12);
        const float* wc = W + c*9;
        #pragma unroll
        for(int ky=0;ky<3;ky++){
            int yy = y+ky-1; if(yy<0||yy>63) continue;
            const float* row = plane + (yy<<6);
            float4 vm = *(const float4*)&row[x0];
            float vl = (x0>0)  ? row[x0-1] : 0.0f;
            float vr = (x0<60) ? row[x0+4] : 0.0f;
            float w0=wc[ky*3+0], w1=wc[ky*3+1], w2=wc[ky*3+2];
            acc0 += w0*vl   + w1*vm.x + w2*vm.y;
            acc1 += w0*vm.x + w1*vm.y + w2*vm.z;
            acc2 += w0*vm.y + w1*vm.z + w2*vm.w;
            acc3 += w0*vm.z + w1*vm.w + w2*vr;
        }
    }
    if(q>=18){
        acc0 = 1.f/(1.f+expf(-acc0)); acc1 = 1.f/(1.f+expf(-acc1));
        acc2 = 1.f/(1.f+expf(-acc2)); acc3 = 1.f/(1.f+expf(-acc3));
    }
    float* dst = OM + ((b*27+q)<<12) + (y<<6) + x0;
    dst[0]=acc0; dst[1]=acc1; dst[2]=acc2; dst[3]=acc3;
}

// ---------------- K5: deformable sampling (channel-last, coalesced) + f32 FMA combine
// Grid: 512 = 8 b x 64 px-tiles(64 px). Block tile: 128 o x 64 px; per tap: gather -> sXf[c][px],
// then K=128 FMA loop; thread = 4 o x 8 px. Weights Wt2[n][c][o] streamed from L1/L2.
__global__ __launch_bounds__(256) void k_deform(fp Ccl, fp OM, fp Wt2, float* D){
    __shared__ float sXf[128*66];    // [c][px], stride 66 (bank stride 2 -> 2-way max, free)
    __shared__ int   sBase[64*4];
    __shared__ float sGw[64*4];
    int b = blockIdx.x >> 6;
    int pix0 = (blockIdx.x & 63) << 6;
    int tid = threadIdx.x;
    int og = tid >> 3, pg = tid & 7;
    int o0 = og*4, p0 = pg*8;
    const float* omb = OM + b*27*4096;
    const float* cb  = Ccl + (size_t)(b<<12)*128;
    float acc[4][8] = {{0.f}};

    for(int n=0;n<9;n++){
        __syncthreads();                         // prev FMA reads done before meta/sXf overwrite
        if(tid < 64){                            // sampling meta, one thread per px
            int pix = pix0 + tid, y = pix>>6, x = pix&63;
            float offx = omb[(n<<12)+pix];
            float offy = omb[((n+9)<<12)+pix];
            float m    = omb[((n+18)<<12)+pix];
            float pxf = (float)(y + n/3) + offx;     // (y+1)+(n/3-1)
            float pyf = (float)(x + n%3) + offy;     // (x+1)+(n%3-1)
            float fx = floorf(pxf), fy = floorf(pyf);
            float qx0 = fminf(fmaxf(fx,0.f),65.f), qx1 = fminf(fmaxf(fx+1.f,0.f),65.f);
            float qy0 = fminf(fmaxf(fy,0.f),65.f), qy1 = fminf(fmaxf(fy+1.f,0.f),65.f);
            float pxc = fminf(fmaxf(pxf,0.f),65.f), pyc = fminf(fmaxf(pyf,0.f),65.f);
            float glt = (1.f+(qx0-pxc))*(1.f+(qy0-pyc))*m;
            float grb = (1.f-(qx1-pxc))*(1.f-(qy1-pyc))*m;
            float glb = (1.f+(qx0-pxc))*(1.f-(qy1-pyc))*m;
            float grt = (1.f-(qx1-pxc))*(1.f+(qy0-pyc))*m;
            int ax0=(int)qx0, ax1=(int)qx1, ay0=(int)qy0, ay1=(int)qy1;
            sBase[tid*4+0] = (ax0>=1&&ax0<=64&&ay0>=1&&ay0<=64) ? (((ax0-1)<<6)+(ay0-1)) : -1;
            sBase[tid*4+1] = (ax1>=1&&ax1<=64&&ay1>=1&&ay1<=64) ? (((ax1-1)<<6)+(ay1-1)) : -1;
            sBase[tid*4+2] = (ax0>=1&&ax0<=64&&ay1>=1&&ay1<=64) ? (((ax0-1)<<6)+(ay1-1)) : -1;
            sBase[tid*4+3] = (ax1>=1&&ax1<=64&&ay0>=1&&ay0<=64) ? (((ax1-1)<<6)+(ay0-1)) : -1;
            sGw[tid*4+0]=glt; sGw[tid*4+1]=grb; sGw[tid*4+2]=glb; sGw[tid*4+3]=grt;
        }
        __syncthreads();
        // gather: e -> (cgroup of 4 ch, px); lanes sweep px (coalesced-ish Ccl row reads,
        // conflict-free stride-1 LDS writes)
        for(int e = tid; e < 2048; e += 256){
            int cg = (e >> 6) << 2, px = e & 63;
            const int* bp = &sBase[px<<2];
            const float* gp = &sGw[px<<2];
            float4 v = make_float4(0.f,0.f,0.f,0.f);
            #pragma unroll
            for(int k=0;k<4;k++){
                int bs = bp[k];
                if(bs>=0){
                    float g = gp[k];
                    float4 r = *(const float4*)&cb[(bs<<7) + cg];
                    v.x += g*r.x; v.y += g*r.y; v.z += g*r.z; v.w += g*r.w;
                }
            }
            sXf[(cg+0)*66+px]=v.x; sXf[(cg+1)*66+px]=v.y;
            sXf[(cg+2)*66+px]=v.z; sXf[(cg+3)*66+px]=v.w;
        }
        __syncthreads();
        const float* wn = Wt2 + (n<<14);
        for(int c=0;c<128;c++){
            float4 w4 = *(const float4*)&wn[(c<<7)+o0];
            float4 xa = *(const float4*)&sXf[c*66+p0];
            float4 xb = *(const float4*)&sXf[c*66+p0+4];
            acc[0][0]+=w4.x*xa.x; acc[0][1]+=w4.x*xa.y; acc[0][2]+=w4.x*xa.z; acc[0][3]+=w4.x*xa.w;
            acc[0][4]+=w4.x*xb.x; acc[0][5]+=w4.x*xb.y; acc[0][6]+=w4.x*xb.z; acc[0][7]+=w4.x*xb.w;
            acc[1][0]+=w4.y*xa.x; acc[1][1]+=w4.y*xa.y; acc[1][2]+=w4.y*xa.z; acc[1][3]+=w4.y*xa.w;
            acc[1][4]+=w4.y*xb.x; acc[1][5]+=w4.y*xb.y; acc[1][6]+=w4.y*xb.z; acc[1][7]+=w4.y*xb.w;
            acc[2][0]+=w4.z*xa.x; acc[2][1]+=w4.z*xa.y; acc[2][2]+=w4.z*xa.z; acc[2][3]+=w4.z*xa.w;
            acc[2][4]+=w4.z*xb.x; acc[2][5]+=w4.z*xb.y; acc[2][6]+=w4.z*xb.z; acc[2][7]+=w4.z*xb.w;
            acc[3][0]+=w4.w*xa.x; acc[3][1]+=w4.w*xa.y; acc[3][2]+=w4.w*xa.z; acc[3][3]+=w4.w*xa.w;
            acc[3][4]+=w4.w*xb.x; acc[3][5]+=w4.w*xb.y; acc[3][6]+=w4.w*xb.z; acc[3][7]+=w4.w*xb.w;
        }
    }
    #pragma unroll
    for(int i=0;i<4;i++){
        float* dst = &D[((b*128+o0+i)<<12)+pix0+p0];
        *(float4*)dst     = make_float4(acc[i][0],acc[i][1],acc[i][2],acc[i][3]);
        *(float4*)(dst+4) = make_float4(acc[i][4],acc[i][5],acc[i][6],acc[i][7]);
    }
}

// ---------------- stats: per-channel mean & rstd (training BN, biased var)
__global__ __launch_bounds__(256) void k_stats(const float* src, float* stats, int statOfs){
    __shared__ double sd[256], sq[256];
    int c = blockIdx.x, tid = threadIdx.x;
    double s=0.0, s2=0.0;
    for(int b=0;b<8;b++){
        const float* p = src + ((b*128+c)<<12);
        for(int i=tid;i<4096;i+=256){ double v = (double)p[i]; s+=v; s2+=v*v; }
    }
    sd[tid]=s; sq[tid]=s2; __syncthreads();
    for(int off=128; off>0; off>>=1){
        if(tid<off){ sd[tid]+=sd[tid+off]; sq[tid]+=sq[tid+off]; }
        __syncthreads();
    }
    if(tid==0){
        double mean = sd[0]/32768.0;
        double var  = sq[0]/32768.0 - mean*mean;
        stats[statOfs+c]     = (float)mean;
        stats[statOfs+128+c] = rsqrtf((float)var + 1e-5f);
    }
}

// ---------------- BN1 + exact GELU
__global__ __launch_bounds__(256) void k_bn_gelu(const float* D, const float* stats, fp g, fp bb, float* G){
    int idx = blockIdx.x*256+threadIdx.x;       // 4,194,304
    int c = (idx>>12)&127;
    float v = (D[idx]-stats[c])*stats[128+c]*g[c] + bb[c];
    G[idx] = 0.5f*v*(1.0f+erff(v*0.70710678118654752f));
}

// ---------------- depthwise 3x3 over 128 ch + bias
__global__ __launch_bounds__(256) void k_dw128(const float* G, fp w, fp bias, float* Hs){
    int idx = blockIdx.x*256 + threadIdx.x;     // 4,194,304
    int x = idx&63, y=(idx>>6)&63, c=(idx>>12)&127, b=idx>>19;
    const float* src = G + ((b*128+c)<<12);
    float acc = bias[c];
    #pragma unroll
    for(int ky=0; ky<3; ky++){
        int yy = y+ky-1; if(yy<0||yy>63) continue;
        #pragma unroll
        for(int kx=0; kx<3; kx++){
            int xx = x+kx-1; if(xx<0||xx>63) continue;
            acc += src[(yy<<6)+xx]*w[c*9+ky*3+kx];
        }
    }
    Hs[idx] = acc;
}

// ---------------- BN2 + ReLU -> f32 out
__global__ __launch_bounds__(256) void k_bn_relu_out(const float* Hs, const float* stats, fp g, fp bb, float* out){
    int idx = blockIdx.x*256+threadIdx.x;       // 4,194,304
    int c = (idx>>12)&127;
    float v = (Hs[idx]-stats[256+c])*stats[384+c]*g[c] + bb[c];
    out[idx] = fmaxf(v,0.f);
}

extern "C" void kernel_launch(void* const* d_in, const int* in_sizes, int n_in,
                              void* d_out, int out_size, void* d_ws, size_t ws_size,
                              hipStream_t stream){
    fp x1   = (fp)d_in[0];
    fp x2   = (fp)d_in[1];
    fp dw_w = (fp)d_in[2];  fp dw_b = (fp)d_in[3];
    fp pw_w = (fp)d_in[4];  fp pw_b = (fp)d_in[5];
    fp p_w  = (fp)d_in[6];  fp p_b  = (fp)d_in[7];
    fp m_w  = (fp)d_in[8];  fp m_b  = (fp)d_in[9];
    fp dcn_w= (fp)d_in[10];
    fp bn1g = (fp)d_in[11]; fp bn1b = (fp)d_in[12];
    fp dw2w = (fp)d_in[13]; fp dw2b = (fp)d_in[14];
    fp bn2g = (fp)d_in[15]; fp bn2b = (fp)d_in[16];

    float* ws    = (float*)d_ws;
    float* A     = ws;                  // 8,388,608 f  (xcat; later OM+Ccl / G+Hs)
    float* Bo    = ws + 8388608;        // 8,388,608 f  (xdw;  later D)
    float* C     = ws + 16777216;       // 4,194,304 f  (h, ch-major)
    float* Wt2   = ws + 20971520;       //   147,456 f  (tap-major dcn_w)
    float* stats = ws + 21118976;       //       512 f
    float* OM  = A;                     // (8,27,4096) = 884,736 f
    float* Ccl = A + 2097152;           // (8,4096,128) ch-last = 4,194,304 f
    float* D   = Bo;                    // (8,128,4096)
    float* G   = A;                     // post-BN1 GELU (OM/Ccl dead)
    float* Hs  = A + 4194304;
    float* out = (float*)d_out;

    k_wt2       <<<576,   256, 0, stream>>>(dcn_w, Wt2);
    k_concat_up <<<32768, 256, 0, stream>>>(x1, x2, A);
    k_dw256     <<<32768, 256, 0, stream>>>(A, dw_w, dw_b, Bo);
    k_pw        <<<1024,  256, 0, stream>>>(Bo, pw_w, pw_b, C, Ccl);
    k_offmask   <<<864,   256, 0, stream>>>(C, p_w, p_b, m_w, m_b, OM);
    k_deform    <<<512,   256, 0, stream>>>(Ccl, OM, Wt2, D);
    k_stats     <<<128,   256, 0, stream>>>(D, stats, 0);
    k_bn_gelu   <<<16384, 256, 0, stream>>>(D, stats, bn1g, bn1b, G);
    k_dw128     <<<16384, 256, 0, stream>>>(G, dw2w, dw2b, Hs);
    k_stats     <<<128,   256, 0, stream>>>(Hs, stats, 256);
    k_bn_relu_out<<<16384,256, 0, stream>>>(Hs, stats, bn2g, bn2b, out);
}

// Round 5
// 612.716 us; speedup vs baseline: 1.3991x; 1.2495x over previous
//
#include <hip/hip_runtime.h>
#include <math.h>

// Problem constants: B=8, spatial 64x64 (HW=4096), C_mid=256, C=128, N=9 taps.
// All inputs/outputs are float32.
typedef const float* fp;

// ---------------- K0: dcn_w (o,c,9) -> Wt2[n][c][o] f32 (tap-major for per-tap combine)
__global__ __launch_bounds__(256) void k_wt2(fp dcn_w, float* Wt2){
    int i = blockIdx.x*256 + threadIdx.x;       // 147456
    int o = i & 127, c = (i >> 7) & 127, n = i >> 14;
    Wt2[i] = dcn_w[o*1152 + c*9 + n];
}

// ---------------- K1: bilinear up2x(align_corners) of x1 + concat with x2 -> A (8,256,64,64)
__global__ __launch_bounds__(256) void k_concat_up(fp x1, fp x2, float* A){
    int idx = blockIdx.x*256 + threadIdx.x;     // 8,388,608
    int x = idx & 63, y = (idx>>6)&63, c = (idx>>12)&255, b = idx>>20;
    float val;
    if (c < 128){
        val = x2[((b*128+c)<<12) + (y<<6) + x];
    } else {
        int cc = c - 128;
        const float s = 31.0f/63.0f;
        float fy = y*s, fx = x*s;
        int iy = (int)fy; if (iy > 30) iy = 30;
        int ix = (int)fx; if (ix > 30) ix = 30;
        float ty = fy - (float)iy, tx = fx - (float)ix;
        fp src = x1 + ((b*128+cc)<<10);
        float v00 = src[iy*32+ix],     v01 = src[iy*32+ix+1];
        float v10 = src[(iy+1)*32+ix], v11 = src[(iy+1)*32+ix+1];
        val = (v00*(1.f-ty)+v10*ty)*(1.f-tx) + (v01*(1.f-ty)+v11*ty)*tx;
    }
    A[idx] = val;
}

// ---------------- K2: depthwise 3x3 SAME over 256 ch + bias -> Bo
__global__ __launch_bounds__(256) void k_dw256(const float* A, fp w, fp bias, float* Bo){
    int idx = blockIdx.x*256 + threadIdx.x;     // 8,388,608
    int x = idx&63, y=(idx>>6)&63, c=(idx>>12)&255, b=idx>>20;
    const float* src = A + ((b*256+c)<<12);
    float acc = bias[c];
    #pragma unroll
    for(int ky=0; ky<3; ky++){
        int yy = y+ky-1; if(yy<0||yy>63) continue;
        #pragma unroll
        for(int kx=0; kx<3; kx++){
            int xx = x+kx-1; if(xx<0||xx>63) continue;
            acc += src[(yy<<6)+xx]*w[c*9+ky*3+kx];
        }
    }
    Bo[idx] = acc;
}

// ---------------- K3: pointwise 256->128 + bias -> Ccl (channel-last only)
__global__ __launch_bounds__(256) void k_pw(const float* Bi, fp w, fp bias, float* Ccl){
    __shared__ float sIn[256*32];
    int bid = blockIdx.x;                       // 1024
    int b = bid >> 7;
    int pix0 = (bid & 127) << 5;
    int tid = threadIdx.x;
    for(int j = tid; j < 256*32; j += 256){
        int c = j >> 5, p = j & 31;
        sIn[j] = Bi[((b*256 + c)<<12) + pix0 + p];
    }
    __syncthreads();
    int og = tid >> 3, pg = tid & 7;
    int o0 = og*4, p0 = pg*4;
    float acc[4][4];
    #pragma unroll
    for(int i=0;i<4;i++){ float bv=bias[o0+i];
        #pragma unroll
        for(int j=0;j<4;j++) acc[i][j]=bv; }
    for(int c=0;c<256;c++){
        float4 xv = *(const float4*)&sIn[(c<<5)+p0];
        float w0=w[(o0+0)*256+c], w1=w[(o0+1)*256+c];
        float w2=w[(o0+2)*256+c], w3=w[(o0+3)*256+c];
        acc[0][0]+=w0*xv.x; acc[0][1]+=w0*xv.y; acc[0][2]+=w0*xv.z; acc[0][3]+=w0*xv.w;
        acc[1][0]+=w1*xv.x; acc[1][1]+=w1*xv.y; acc[1][2]+=w1*xv.z; acc[1][3]+=w1*xv.w;
        acc[2][0]+=w2*xv.x; acc[2][1]+=w2*xv.y; acc[2][2]+=w2*xv.z; acc[2][3]+=w2*xv.w;
        acc[3][0]+=w3*xv.x; acc[3][1]+=w3*xv.y; acc[3][2]+=w3*xv.z; acc[3][3]+=w3*xv.w;
    }
    #pragma unroll
    for(int j=0;j<4;j++){
        int px = pix0 + p0 + j;
        *(float4*)&Ccl[((size_t)(b<<12) + px)*128 + o0] =
            make_float4(acc[0][j],acc[1][j],acc[2][j],acc[3][j]);
    }
}

// ---------------- K4: offset(18)+mask(9, sigmoid) 3x3 conv from Ccl -> OM (8,27,4096)
// Grid: 256 = 8 b x 32 row-pairs. Block: 2 output rows (128 px) x 27 q (pad 32).
// Thread = 2 q x 8 px. 8 c-chunks of 16: stage sX (4 rows x 16c x 68 halo'd) + sW, then FMA.
__global__ __launch_bounds__(256) void k_offmask(fp Ccl, fp pw, fp pb, fp mw, fp mb, float* OM){
    __shared__ float sX[4*16*68];    // [(row*16+c)][68], rows 272B (16B-aligned)
    __shared__ float sW[16*9*30];    // [(c*9+tap)*30 + q], stride 30: 2-way banks, 8B-aligned
    int b = blockIdx.x >> 5;
    int y0 = (blockIdx.x & 31) << 1;
    int tid = threadIdx.x;
    int qp = tid >> 4, pxg = tid & 15;
    int q0 = qp << 1;                 // 0..30
    int ry = pxg >> 3;                // which of the 2 output rows
    int x0 = (pxg & 7) << 3;          // 0..56
    const float* cb = Ccl + (size_t)(b<<12)*128;
    float acc[2][8] = {{0.f}};

    for(int chunk=0; chunk<8; chunk++){
        int c0 = chunk << 4;
        __syncthreads();
        // stage sX: 1088 float4 (4 rows x 68 px x 4 cgroups)
        for(int j=tid; j<1088; j+=256){
            int cg = j & 3; int t = j >> 2; int pxh = t % 68; int row = t / 68;
            int yy = y0 + row - 1; int xx = pxh - 1;
            float4 v = make_float4(0.f,0.f,0.f,0.f);
            if(yy>=0 && yy<64 && xx>=0 && xx<64)
                v = *(const float4*)&cb[(size_t)((yy<<6)+xx)*128 + c0 + (cg<<2)];
            int ci = (row*16 + (cg<<2))*68 + pxh;
            sX[ci] = v.x; sX[ci+68] = v.y; sX[ci+136] = v.z; sX[ci+204] = v.w;
        }
        // stage sW: 16c x 9tap x 27q (contiguous 144-float runs per q in global)
        for(int j=tid; j<3888; j+=256){
            int qq = j / 144; int rem = j - qq*144;    // rem = c*9+tap
            float wv = (qq<18) ? pw[qq*1152 + c0*9 + rem]
                               : mw[(qq-18)*1152 + c0*9 + rem];
            sW[rem*30 + qq] = wv;
        }
        __syncthreads();
        for(int ci=0; ci<16; ci++){
            #pragma unroll
            for(int ky=0; ky<3; ky++){
                const float* xr = &sX[(((ry+ky)*16 + ci)*68) + x0];
                float xv[10];
                *(float4*)&xv[0] = *(const float4*)&xr[0];
                *(float4*)&xv[4] = *(const float4*)&xr[4];
                *(float2*)&xv[8] = *(const float2*)&xr[8];
                const float* wb = &sW[(ci*9 + ky*3)*30 + q0];
                float2 w0 = *(const float2*)&wb[0];
                float2 w1 = *(const float2*)&wb[30];
                float2 w2 = *(const float2*)&wb[60];
                #pragma unroll
                for(int j=0;j<8;j++){
                    acc[0][j] += w0.x*xv[j] + w1.x*xv[j+1] + w2.x*xv[j+2];
                    acc[1][j] += w0.y*xv[j] + w1.y*xv[j+1] + w2.y*xv[j+2];
                }
            }
        }
    }
    #pragma unroll
    for(int qi=0; qi<2; qi++){
        int q = q0 + qi;
        if(q >= 27) continue;
        float bias = (q<18) ? pb[q] : mb[q-18];
        float o[8];
        #pragma unroll
        for(int j=0;j<8;j++){
            float v = acc[qi][j] + bias;
            o[j] = (q>=18) ? 1.f/(1.f+expf(-v)) : v;
        }
        float* dst = OM + ((b*27+q)<<12) + ((y0+ry)<<6) + x0;
        *(float4*)dst     = make_float4(o[0],o[1],o[2],o[3]);
        *(float4*)(dst+4) = make_float4(o[4],o[5],o[6],o[7]);
    }
}

// ---------------- K5: deformable sampling (channel-last, coalesced) + f32 FMA combine
__global__ __launch_bounds__(256) void k_deform(fp Ccl, fp OM, fp Wt2, float* D){
    __shared__ float sXf[128*66];    // [c][px], stride 66 (bank stride 2 -> free)
    __shared__ int   sBase[64*4];
    __shared__ float sGw[64*4];
    int b = blockIdx.x >> 6;
    int pix0 = (blockIdx.x & 63) << 6;
    int tid = threadIdx.x;
    int og = tid >> 3, pg = tid & 7;
    int o0 = og*4, p0 = pg*8;
    const float* omb = OM + b*27*4096;
    const float* cb  = Ccl + (size_t)(b<<12)*128;
    float acc[4][8] = {{0.f}};

    for(int n=0;n<9;n++){
        __syncthreads();
        if(tid < 64){
            int pix = pix0 + tid, y = pix>>6, x = pix&63;
            float offx = omb[(n<<12)+pix];
            float offy = omb[((n+9)<<12)+pix];
            float m    = omb[((n+18)<<12)+pix];
            float pxf = (float)(y + n/3) + offx;
            float pyf = (float)(x + n%3) + offy;
            float fx = floorf(pxf), fy = floorf(pyf);
            float qx0 = fminf(fmaxf(fx,0.f),65.f), qx1 = fminf(fmaxf(fx+1.f,0.f),65.f);
            float qy0 = fminf(fmaxf(fy,0.f),65.f), qy1 = fminf(fmaxf(fy+1.f,0.f),65.f);
            float pxc = fminf(fmaxf(pxf,0.f),65.f), pyc = fminf(fmaxf(pyf,0.f),65.f);
            float glt = (1.f+(qx0-pxc))*(1.f+(qy0-pyc))*m;
            float grb = (1.f-(qx1-pxc))*(1.f-(qy1-pyc))*m;
            float glb = (1.f+(qx0-pxc))*(1.f-(qy1-pyc))*m;
            float grt = (1.f-(qx1-pxc))*(1.f+(qy0-pyc))*m;
            int ax0=(int)qx0, ax1=(int)qx1, ay0=(int)qy0, ay1=(int)qy1;
            sBase[tid*4+0] = (ax0>=1&&ax0<=64&&ay0>=1&&ay0<=64) ? (((ax0-1)<<6)+(ay0-1)) : -1;
            sBase[tid*4+1] = (ax1>=1&&ax1<=64&&ay1>=1&&ay1<=64) ? (((ax1-1)<<6)+(ay1-1)) : -1;
            sBase[tid*4+2] = (ax0>=1&&ax0<=64&&ay1>=1&&ay1<=64) ? (((ax0-1)<<6)+(ay1-1)) : -1;
            sBase[tid*4+3] = (ax1>=1&&ax1<=64&&ay0>=1&&ay0<=64) ? (((ax1-1)<<6)+(ay0-1)) : -1;
            sGw[tid*4+0]=glt; sGw[tid*4+1]=grb; sGw[tid*4+2]=glb; sGw[tid*4+3]=grt;
        }
        __syncthreads();
        for(int e = tid; e < 2048; e += 256){
            int cg = (e >> 6) << 2, px = e & 63;
            const int* bp = &sBase[px<<2];
            const float* gp = &sGw[px<<2];
            float4 v = make_float4(0.f,0.f,0.f,0.f);
            #pragma unroll
            for(int k=0;k<4;k++){
                int bs = bp[k];
                if(bs>=0){
                    float g = gp[k];
                    float4 r = *(const float4*)&cb[(bs<<7) + cg];
                    v.x += g*r.x; v.y += g*r.y; v.z += g*r.z; v.w += g*r.w;
                }
            }
            sXf[(cg+0)*66+px]=v.x; sXf[(cg+1)*66+px]=v.y;
            sXf[(cg+2)*66+px]=v.z; sXf[(cg+3)*66+px]=v.w;
        }
        __syncthreads();
        const float* wn = Wt2 + (n<<14);
        for(int c=0;c<128;c++){
            float4 w4 = *(const float4*)&wn[(c<<7)+o0];
            float4 xa = *(const float4*)&sXf[c*66+p0];
            float4 xb = *(const float4*)&sXf[c*66+p0+4];
            acc[0][0]+=w4.x*xa.x; acc[0][1]+=w4.x*xa.y; acc[0][2]+=w4.x*xa.z; acc[0][3]+=w4.x*xa.w;
            acc[0][4]+=w4.x*xb.x; acc[0][5]+=w4.x*xb.y; acc[0][6]+=w4.x*xb.z; acc[0][7]+=w4.x*xb.w;
            acc[1][0]+=w4.y*xa.x; acc[1][1]+=w4.y*xa.y; acc[1][2]+=w4.y*xa.z; acc[1][3]+=w4.y*xa.w;
            acc[1][4]+=w4.y*xb.x; acc[1][5]+=w4.y*xb.y; acc[1][6]+=w4.y*xb.z; acc[1][7]+=w4.y*xb.w;
            acc[2][0]+=w4.z*xa.x; acc[2][1]+=w4.z*xa.y; acc[2][2]+=w4.z*xa.z; acc[2][3]+=w4.z*xa.w;
            acc[2][4]+=w4.z*xb.x; acc[2][5]+=w4.z*xb.y; acc[2][6]+=w4.z*xb.z; acc[2][7]+=w4.z*xb.w;
            acc[3][0]+=w4.w*xa.x; acc[3][1]+=w4.w*xa.y; acc[3][2]+=w4.w*xa.z; acc[3][3]+=w4.w*xa.w;
            acc[3][4]+=w4.w*xb.x; acc[3][5]+=w4.w*xb.y; acc[3][6]+=w4.w*xb.z; acc[3][7]+=w4.w*xb.w;
        }
    }
    #pragma unroll
    for(int i=0;i<4;i++){
        float* dst = &D[((b*128+o0+i)<<12)+pix0+p0];
        *(float4*)dst     = make_float4(acc[i][0],acc[i][1],acc[i][2],acc[i][3]);
        *(float4*)(dst+4) = make_float4(acc[i][4],acc[i][5],acc[i][6],acc[i][7]);
    }
}

// ---------------- stats: per-channel mean & rstd (training BN, biased var)
__global__ __launch_bounds__(256) void k_stats(const float* src, float* stats, int statOfs){
    __shared__ double sd[256], sq[256];
    int c = blockIdx.x, tid = threadIdx.x;
    double s=0.0, s2=0.0;
    for(int b=0;b<8;b++){
        const float* p = src + ((b*128+c)<<12);
        for(int i=tid;i<4096;i+=256){ double v = (double)p[i]; s+=v; s2+=v*v; }
    }
    sd[tid]=s; sq[tid]=s2; __syncthreads();
    for(int off=128; off>0; off>>=1){
        if(tid<off){ sd[tid]+=sd[tid+off]; sq[tid]+=sq[tid+off]; }
        __syncthreads();
    }
    if(tid==0){
        double mean = sd[0]/32768.0;
        double var  = sq[0]/32768.0 - mean*mean;
        stats[statOfs+c]     = (float)mean;
        stats[statOfs+128+c] = rsqrtf((float)var + 1e-5f);
    }
}

// ---------------- BN1 + exact GELU
__global__ __launch_bounds__(256) void k_bn_gelu(const float* D, const float* stats, fp g, fp bb, float* G){
    int idx = blockIdx.x*256+threadIdx.x;       // 4,194,304
    int c = (idx>>12)&127;
    float v = (D[idx]-stats[c])*stats[128+c]*g[c] + bb[c];
    G[idx] = 0.5f*v*(1.0f+erff(v*0.70710678118654752f));
}

// ---------------- depthwise 3x3 over 128 ch + bias
__global__ __launch_bounds__(256) void k_dw128(const float* G, fp w, fp bias, float* Hs){
    int idx = blockIdx.x*256 + threadIdx.x;     // 4,194,304
    int x = idx&63, y=(idx>>6)&63, c=(idx>>12)&127, b=idx>>19;
    const float* src = G + ((b*128+c)<<12);
    float acc = bias[c];
    #pragma unroll
    for(int ky=0; ky<3; ky++){
        int yy = y+ky-1; if(yy<0||yy>63) continue;
        #pragma unroll
        for(int kx=0; kx<3; kx++){
            int xx = x+kx-1; if(xx<0||xx>63) continue;
            acc += src[(yy<<6)+xx]*w[c*9+ky*3+kx];
        }
    }
    Hs[idx] = acc;
}

// ---------------- BN2 + ReLU -> f32 out
__global__ __launch_bounds__(256) void k_bn_relu_out(const float* Hs, const float* stats, fp g, fp bb, float* out){
    int idx = blockIdx.x*256+threadIdx.x;       // 4,194,304
    int c = (idx>>12)&127;
    float v = (Hs[idx]-stats[256+c])*stats[384+c]*g[c] + bb[c];
    out[idx] = fmaxf(v,0.f);
}

extern "C" void kernel_launch(void* const* d_in, const int* in_sizes, int n_in,
                              void* d_out, int out_size, void* d_ws, size_t ws_size,
                              hipStream_t stream){
    fp x1   = (fp)d_in[0];
    fp x2   = (fp)d_in[1];
    fp dw_w = (fp)d_in[2];  fp dw_b = (fp)d_in[3];
    fp pw_w = (fp)d_in[4];  fp pw_b = (fp)d_in[5];
    fp p_w  = (fp)d_in[6];  fp p_b  = (fp)d_in[7];
    fp m_w  = (fp)d_in[8];  fp m_b  = (fp)d_in[9];
    fp dcn_w= (fp)d_in[10];
    fp bn1g = (fp)d_in[11]; fp bn1b = (fp)d_in[12];
    fp dw2w = (fp)d_in[13]; fp dw2b = (fp)d_in[14];
    fp bn2g = (fp)d_in[15]; fp bn2b = (fp)d_in[16];

    float* ws    = (float*)d_ws;
    float* A     = ws;                  // 8,388,608 f  (xcat; later OM+Ccl / G+Hs)
    float* Bo    = ws + 8388608;        // 8,388,608 f  (xdw;  later D)
    float* Wt2   = ws + 20971520;       //   147,456 f  (tap-major dcn_w)
    float* stats = ws + 21118976;       //       512 f
    float* OM  = A;                     // (8,27,4096) = 884,736 f
    float* Ccl = A + 2097152;           // (8,4096,128) ch-last = 4,194,304 f
    float* D   = Bo;                    // (8,128,4096)
    float* G   = A;                     // post-BN1 GELU (OM/Ccl dead)
    float* Hs  = A + 4194304;
    float* out = (float*)d_out;

    k_wt2       <<<576,   256, 0, stream>>>(dcn_w, Wt2);
    k_concat_up <<<32768, 256, 0, stream>>>(x1, x2, A);
    k_dw256     <<<32768, 256, 0, stream>>>(A, dw_w, dw_b, Bo);
    k_pw        <<<1024,  256, 0, stream>>>(Bo, pw_w, pw_b, Ccl);
    k_offmask   <<<256,   256, 0, stream>>>(Ccl, p_w, p_b, m_w, m_b, OM);
    k_deform    <<<512,   256, 0, stream>>>(Ccl, OM, Wt2, D);
    k_stats     <<<128,   256, 0, stream>>>(D, stats, 0);
    k_bn_gelu   <<<16384, 256, 0, stream>>>(D, stats, bn1g, bn1b, G);
    k_dw128     <<<16384, 256, 0, stream>>>(G, dw2w, dw2b, Hs);
    k_stats     <<<128,   256, 0, stream>>>(Hs, stats, 256);
    k_bn_relu_out<<<16384,256, 0, stream>>>(Hs, stats, bn2g, bn2b, out);
}

// Round 6
// 598.819 us; speedup vs baseline: 1.4316x; 1.0232x over previous
//
#include <hip/hip_runtime.h>
#include <math.h>

// Problem constants: B=8, spatial 64x64 (HW=4096), C_mid=256, C=128, N=9 taps.
// All inputs/outputs are float32.
typedef const float* fp;

// ---------------- K0: dcn_w (o,c,9) -> Wt2[n][c][o] f32 (tap-major for per-tap combine)
__global__ __launch_bounds__(256) void k_wt2(fp dcn_w, float* Wt2){
    int i = blockIdx.x*256 + threadIdx.x;       // 147456
    int o = i & 127, c = (i >> 7) & 127, n = i >> 14;
    Wt2[i] = dcn_w[o*1152 + c*9 + n];
}

// ---------------- K1: bilinear up2x(align_corners) of x1 + concat with x2 -> A (8,256,64,64)
__global__ __launch_bounds__(256) void k_concat_up(fp x1, fp x2, float* A){
    int idx = blockIdx.x*256 + threadIdx.x;     // 8,388,608
    int x = idx & 63, y = (idx>>6)&63, c = (idx>>12)&255, b = idx>>20;
    float val;
    if (c < 128){
        val = x2[((b*128+c)<<12) + (y<<6) + x];
    } else {
        int cc = c - 128;
        const float s = 31.0f/63.0f;
        float fy = y*s, fx = x*s;
        int iy = (int)fy; if (iy > 30) iy = 30;
        int ix = (int)fx; if (ix > 30) ix = 30;
        float ty = fy - (float)iy, tx = fx - (float)ix;
        fp src = x1 + ((b*128+cc)<<10);
        float v00 = src[iy*32+ix],     v01 = src[iy*32+ix+1];
        float v10 = src[(iy+1)*32+ix], v11 = src[(iy+1)*32+ix+1];
        val = (v00*(1.f-ty)+v10*ty)*(1.f-tx) + (v01*(1.f-ty)+v11*ty)*tx;
    }
    A[idx] = val;
}

// ---------------- K2: depthwise 3x3 SAME over 256 ch + bias -> Bo
__global__ __launch_bounds__(256) void k_dw256(const float* A, fp w, fp bias, float* Bo){
    int idx = blockIdx.x*256 + threadIdx.x;     // 8,388,608
    int x = idx&63, y=(idx>>6)&63, c=(idx>>12)&255, b=idx>>20;
    const float* src = A + ((b*256+c)<<12);
    float acc = bias[c];
    #pragma unroll
    for(int ky=0; ky<3; ky++){
        int yy = y+ky-1; if(yy<0||yy>63) continue;
        #pragma unroll
        for(int kx=0; kx<3; kx++){
            int xx = x+kx-1; if(xx<0||xx>63) continue;
            acc += src[(yy<<6)+xx]*w[c*9+ky*3+kx];
        }
    }
    Bo[idx] = acc;
}

// ---------------- K3: pointwise 256->128 + bias -> Ccl (channel-last only)
__global__ __launch_bounds__(256) void k_pw(const float* Bi, fp w, fp bias, float* Ccl){
    __shared__ float sIn[256*32];
    int bid = blockIdx.x;                       // 1024
    int b = bid >> 7;
    int pix0 = (bid & 127) << 5;
    int tid = threadIdx.x;
    for(int j = tid; j < 256*32; j += 256){
        int c = j >> 5, p = j & 31;
        sIn[j] = Bi[((b*256 + c)<<12) + pix0 + p];
    }
    __syncthreads();
    int og = tid >> 3, pg = tid & 7;
    int o0 = og*4, p0 = pg*4;
    float acc[4][4];
    #pragma unroll
    for(int i=0;i<4;i++){ float bv=bias[o0+i];
        #pragma unroll
        for(int j=0;j<4;j++) acc[i][j]=bv; }
    for(int c=0;c<256;c++){
        float4 xv = *(const float4*)&sIn[(c<<5)+p0];
        float w0=w[(o0+0)*256+c], w1=w[(o0+1)*256+c];
        float w2=w[(o0+2)*256+c], w3=w[(o0+3)*256+c];
        acc[0][0]+=w0*xv.x; acc[0][1]+=w0*xv.y; acc[0][2]+=w0*xv.z; acc[0][3]+=w0*xv.w;
        acc[1][0]+=w1*xv.x; acc[1][1]+=w1*xv.y; acc[1][2]+=w1*xv.z; acc[1][3]+=w1*xv.w;
        acc[2][0]+=w2*xv.x; acc[2][1]+=w2*xv.y; acc[2][2]+=w2*xv.z; acc[2][3]+=w2*xv.w;
        acc[3][0]+=w3*xv.x; acc[3][1]+=w3*xv.y; acc[3][2]+=w3*xv.z; acc[3][3]+=w3*xv.w;
    }
    #pragma unroll
    for(int j=0;j<4;j++){
        int px = pix0 + p0 + j;
        *(float4*)&Ccl[((size_t)(b<<12) + px)*128 + o0] =
            make_float4(acc[0][j],acc[1][j],acc[2][j],acc[3][j]);
    }
}

// ---------------- K4: offset(18)+mask(9, sigmoid) 3x3 conv from Ccl -> OM (8,27,4096)
// Grid: 256 = 32 row-pairs x 8 b; b = blockIdx&7 for XCD L2 affinity.
__global__ __launch_bounds__(256) void k_offmask(fp Ccl, fp pw, fp pb, fp mw, fp mb, float* OM){
    __shared__ float sX[4*16*68];    // [(row*16+c)][68], rows 272B (16B-aligned)
    __shared__ float sW[16*9*30];    // [(c*9+tap)*30 + q], stride 30: 2-way banks, 8B-aligned
    int b = blockIdx.x & 7;
    int y0 = (blockIdx.x >> 3) << 1;
    int tid = threadIdx.x;
    int qp = tid >> 4, pxg = tid & 15;
    int q0 = qp << 1;                 // 0..30
    int ry = pxg >> 3;                // which of the 2 output rows
    int x0 = (pxg & 7) << 3;          // 0..56
    const float* cb = Ccl + (size_t)(b<<12)*128;
    float acc[2][8] = {{0.f}};

    for(int chunk=0; chunk<8; chunk++){
        int c0 = chunk << 4;
        __syncthreads();
        for(int j=tid; j<1088; j+=256){
            int cg = j & 3; int t = j >> 2; int pxh = t % 68; int row = t / 68;
            int yy = y0 + row - 1; int xx = pxh - 1;
            float4 v = make_float4(0.f,0.f,0.f,0.f);
            if(yy>=0 && yy<64 && xx>=0 && xx<64)
                v = *(const float4*)&cb[(size_t)((yy<<6)+xx)*128 + c0 + (cg<<2)];
            int ci = (row*16 + (cg<<2))*68 + pxh;
            sX[ci] = v.x; sX[ci+68] = v.y; sX[ci+136] = v.z; sX[ci+204] = v.w;
        }
        for(int j=tid; j<3888; j+=256){
            int qq = j / 144; int rem = j - qq*144;    // rem = c*9+tap
            float wv = (qq<18) ? pw[qq*1152 + c0*9 + rem]
                               : mw[(qq-18)*1152 + c0*9 + rem];
            sW[rem*30 + qq] = wv;
        }
        __syncthreads();
        for(int ci=0; ci<16; ci++){
            #pragma unroll
            for(int ky=0; ky<3; ky++){
                const float* xr = &sX[(((ry+ky)*16 + ci)*68) + x0];
                float xv[10];
                *(float4*)&xv[0] = *(const float4*)&xr[0];
                *(float4*)&xv[4] = *(const float4*)&xr[4];
                *(float2*)&xv[8] = *(const float2*)&xr[8];
                const float* wb = &sW[(ci*9 + ky*3)*30 + q0];
                float2 w0 = *(const float2*)&wb[0];
                float2 w1 = *(const float2*)&wb[30];
                float2 w2 = *(const float2*)&wb[60];
                #pragma unroll
                for(int j=0;j<8;j++){
                    acc[0][j] += w0.x*xv[j] + w1.x*xv[j+1] + w2.x*xv[j+2];
                    acc[1][j] += w0.y*xv[j] + w1.y*xv[j+1] + w2.y*xv[j+2];
                }
            }
        }
    }
    #pragma unroll
    for(int qi=0; qi<2; qi++){
        int q = q0 + qi;
        if(q >= 27) continue;
        float bias = (q<18) ? pb[q] : mb[q-18];
        float o[8];
        #pragma unroll
        for(int j=0;j<8;j++){
            float v = acc[qi][j] + bias;
            o[j] = (q>=18) ? 1.f/(1.f+expf(-v)) : v;
        }
        float* dst = OM + ((b*27+q)<<12) + ((y0+ry)<<6) + x0;
        *(float4*)dst     = make_float4(o[0],o[1],o[2],o[3]);
        *(float4*)(dst+4) = make_float4(o[4],o[5],o[6],o[7]);
    }
}

// ---------------- K5: deformable sampling + f32 FMA combine
// Grid: 1024 = 128 px-tiles(32 px) x 8 b; b = blockIdx&7 (XCD L2 affinity: 2MB batch
// slice + 0.6MB Wt2 fit the 4MB XCD L2). Block: 128 o x 32 px; thread 4o x 4px.
__global__ __launch_bounds__(256) void k_deform(fp Ccl, fp OM, fp Wt2, float* D){
    __shared__ float sXf[128*34];    // [c][px], stride 34 (8 b128/wave span all banks)
    __shared__ int   sBase[32*4];
    __shared__ float sGw[32*4];
    int b = blockIdx.x & 7;
    int pix0 = (blockIdx.x >> 3) << 5;
    int tid = threadIdx.x;
    int og = tid >> 3, pg = tid & 7;
    int o0 = og*4, p0 = pg*4;
    const float* omb = OM + b*27*4096;
    const float* cb  = Ccl + (size_t)(b<<12)*128;
    float acc[4][4] = {{0.f}};

    for(int n=0;n<9;n++){
        __syncthreads();                 // prev iter's sBase/sXf reads done
        if(tid < 32){                    // sampling meta, one thread per px
            int pix = pix0 + tid, y = pix>>6, x = pix&63;
            float offx = omb[(n<<12)+pix];
            float offy = omb[((n+9)<<12)+pix];
            float m    = omb[((n+18)<<12)+pix];
            float pxf = (float)(y + n/3) + offx;     // (y+1)+(n/3-1)
            float pyf = (float)(x + n%3) + offy;     // (x+1)+(n%3-1)
            float fx = floorf(pxf), fy = floorf(pyf);
            float qx0 = fminf(fmaxf(fx,0.f),65.f), qx1 = fminf(fmaxf(fx+1.f,0.f),65.f);
            float qy0 = fminf(fmaxf(fy,0.f),65.f), qy1 = fminf(fmaxf(fy+1.f,0.f),65.f);
            float pxc = fminf(fmaxf(pxf,0.f),65.f), pyc = fminf(fmaxf(pyf,0.f),65.f);
            float glt = (1.f+(qx0-pxc))*(1.f+(qy0-pyc))*m;
            float grb = (1.f-(qx1-pxc))*(1.f-(qy1-pyc))*m;
            float glb = (1.f+(qx0-pxc))*(1.f-(qy1-pyc))*m;
            float grt = (1.f-(qx1-pxc))*(1.f+(qy0-pyc))*m;
            int ax0=(int)qx0, ax1=(int)qx1, ay0=(int)qy0, ay1=(int)qy1;
            sBase[tid*4+0] = (ax0>=1&&ax0<=64&&ay0>=1&&ay0<=64) ? (((ax0-1)<<6)+(ay0-1)) : -1;
            sBase[tid*4+1] = (ax1>=1&&ax1<=64&&ay1>=1&&ay1<=64) ? (((ax1-1)<<6)+(ay1-1)) : -1;
            sBase[tid*4+2] = (ax0>=1&&ax0<=64&&ay1>=1&&ay1<=64) ? (((ax0-1)<<6)+(ay1-1)) : -1;
            sBase[tid*4+3] = (ax1>=1&&ax1<=64&&ay0>=1&&ay0<=64) ? (((ax1-1)<<6)+(ay0-1)) : -1;
            sGw[tid*4+0]=glt; sGw[tid*4+1]=grb; sGw[tid*4+2]=glb; sGw[tid*4+3]=grt;
        }
        __syncthreads();
        // gather: 1024 = 32 cgroups x 32 px; 4 iters/thread; Ccl reads are L2-hot
        for(int e = tid; e < 1024; e += 256){
            int cg = (e >> 5) << 2, px = e & 31;
            const int* bp = &sBase[px<<2];
            const float* gp = &sGw[px<<2];
            float4 v = make_float4(0.f,0.f,0.f,0.f);
            #pragma unroll
            for(int k=0;k<4;k++){
                int bs = bp[k];
                if(bs>=0){
                    float g = gp[k];
                    float4 r = *(const float4*)&cb[(bs<<7) + cg];
                    v.x += g*r.x; v.y += g*r.y; v.z += g*r.z; v.w += g*r.w;
                }
            }
            sXf[(cg+0)*34+px]=v.x; sXf[(cg+1)*34+px]=v.y;
            sXf[(cg+2)*34+px]=v.z; sXf[(cg+3)*34+px]=v.w;
        }
        __syncthreads();
        const float* wn = Wt2 + (n<<14);
        for(int c=0;c<128;c++){
            float4 w4 = *(const float4*)&wn[(c<<7)+o0];
            float4 xa = *(const float4*)&sXf[c*34+p0];
            acc[0][0]+=w4.x*xa.x; acc[0][1]+=w4.x*xa.y; acc[0][2]+=w4.x*xa.z; acc[0][3]+=w4.x*xa.w;
            acc[1][0]+=w4.y*xa.x; acc[1][1]+=w4.y*xa.y; acc[1][2]+=w4.y*xa.z; acc[1][3]+=w4.y*xa.w;
            acc[2][0]+=w4.z*xa.x; acc[2][1]+=w4.z*xa.y; acc[2][2]+=w4.z*xa.z; acc[2][3]+=w4.z*xa.w;
            acc[3][0]+=w4.w*xa.x; acc[3][1]+=w4.w*xa.y; acc[3][2]+=w4.w*xa.z; acc[3][3]+=w4.w*xa.w;
        }
    }
    #pragma unroll
    for(int i=0;i<4;i++){
        *(float4*)&D[((b*128+o0+i)<<12)+pix0+p0] =
            make_float4(acc[i][0],acc[i][1],acc[i][2],acc[i][3]);
    }
}

// ---------------- stats: per-channel mean & rstd (training BN, biased var)
__global__ __launch_bounds__(256) void k_stats(const float* src, float* stats, int statOfs){
    __shared__ double sd[256], sq[256];
    int c = blockIdx.x, tid = threadIdx.x;
    double s=0.0, s2=0.0;
    for(int b=0;b<8;b++){
        const float* p = src + ((b*128+c)<<12);
        for(int i=tid;i<4096;i+=256){ double v = (double)p[i]; s+=v; s2+=v*v; }
    }
    sd[tid]=s; sq[tid]=s2; __syncthreads();
    for(int off=128; off>0; off>>=1){
        if(tid<off){ sd[tid]+=sd[tid+off]; sq[tid]+=sq[tid+off]; }
        __syncthreads();
    }
    if(tid==0){
        double mean = sd[0]/32768.0;
        double var  = sq[0]/32768.0 - mean*mean;
        stats[statOfs+c]     = (float)mean;
        stats[statOfs+128+c] = rsqrtf((float)var + 1e-5f);
    }
}

// ---------------- BN1 + exact GELU
__global__ __launch_bounds__(256) void k_bn_gelu(const float* D, const float* stats, fp g, fp bb, float* G){
    int idx = blockIdx.x*256+threadIdx.x;       // 4,194,304
    int c = (idx>>12)&127;
    float v = (D[idx]-stats[c])*stats[128+c]*g[c] + bb[c];
    G[idx] = 0.5f*v*(1.0f+erff(v*0.70710678118654752f));
}

// ---------------- depthwise 3x3 over 128 ch + bias
__global__ __launch_bounds__(256) void k_dw128(const float* G, fp w, fp bias, float* Hs){
    int idx = blockIdx.x*256 + threadIdx.x;     // 4,194,304
    int x = idx&63, y=(idx>>6)&63, c=(idx>>12)&127, b=idx>>19;
    const float* src = G + ((b*128+c)<<12);
    float acc = bias[c];
    #pragma unroll
    for(int ky=0; ky<3; ky++){
        int yy = y+ky-1; if(yy<0||yy>63) continue;
        #pragma unroll
        for(int kx=0; kx<3; kx++){
            int xx = x+kx-1; if(xx<0||xx>63) continue;
            acc += src[(yy<<6)+xx]*w[c*9+ky*3+kx];
        }
    }
    Hs[idx] = acc;
}

// ---------------- BN2 + ReLU -> f32 out
__global__ __launch_bounds__(256) void k_bn_relu_out(const float* Hs, const float* stats, fp g, fp bb, float* out){
    int idx = blockIdx.x*256+threadIdx.x;       // 4,194,304
    int c = (idx>>12)&127;
    float v = (Hs[idx]-stats[256+c])*stats[384+c]*g[c] + bb[c];
    out[idx] = fmaxf(v,0.f);
}

extern "C" void kernel_launch(void* const* d_in, const int* in_sizes, int n_in,
                              void* d_out, int out_size, void* d_ws, size_t ws_size,
                              hipStream_t stream){
    fp x1   = (fp)d_in[0];
    fp x2   = (fp)d_in[1];
    fp dw_w = (fp)d_in[2];  fp dw_b = (fp)d_in[3];
    fp pw_w = (fp)d_in[4];  fp pw_b = (fp)d_in[5];
    fp p_w  = (fp)d_in[6];  fp p_b  = (fp)d_in[7];
    fp m_w  = (fp)d_in[8];  fp m_b  = (fp)d_in[9];
    fp dcn_w= (fp)d_in[10];
    fp bn1g = (fp)d_in[11]; fp bn1b = (fp)d_in[12];
    fp dw2w = (fp)d_in[13]; fp dw2b = (fp)d_in[14];
    fp bn2g = (fp)d_in[15]; fp bn2b = (fp)d_in[16];

    float* ws    = (float*)d_ws;
    float* A     = ws;                  // 8,388,608 f  (xcat; later OM+Ccl / G+Hs)
    float* Bo    = ws + 8388608;        // 8,388,608 f  (xdw;  later D)
    float* Wt2   = ws + 20971520;       //   147,456 f  (tap-major dcn_w)
    float* stats = ws + 21118976;       //       512 f
    float* OM  = A;                     // (8,27,4096) = 884,736 f
    float* Ccl = A + 2097152;           // (8,4096,128) ch-last = 4,194,304 f
    float* D   = Bo;                    // (8,128,4096)
    float* G   = A;                     // post-BN1 GELU (OM/Ccl dead)
    float* Hs  = A + 4194304;
    float* out = (float*)d_out;

    k_wt2       <<<576,   256, 0, stream>>>(dcn_w, Wt2);
    k_concat_up <<<32768, 256, 0, stream>>>(x1, x2, A);
    k_dw256     <<<32768, 256, 0, stream>>>(A, dw_w, dw_b, Bo);
    k_pw        <<<1024,  256, 0, stream>>>(Bo, pw_w, pw_b, Ccl);
    k_offmask   <<<256,   256, 0, stream>>>(Ccl, p_w, p_b, m_w, m_b, OM);
    k_deform    <<<1024,  256, 0, stream>>>(Ccl, OM, Wt2, D);
    k_stats     <<<128,   256, 0, stream>>>(D, stats, 0);
    k_bn_gelu   <<<16384, 256, 0, stream>>>(D, stats, bn1g, bn1b, G);
    k_dw128     <<<16384, 256, 0, stream>>>(G, dw2w, dw2b, Hs);
    k_stats     <<<128,   256, 0, stream>>>(Hs, stats, 256);
    k_bn_relu_out<<<16384,256, 0, stream>>>(Hs, stats, bn2g, bn2b, out);
}